// Round 8
// baseline (402.031 us; speedup 1.0000x reference)
//
#include <hip/hip_runtime.h>
#include <hip/hip_fp16.h>
#include <math.h>

#define NROWS 50000
#define D 128
#define KNB 16

typedef _Float16 f16;
typedef _Float16 f16x8 __attribute__((ext_vector_type(8)));
typedef float f32x4 __attribute__((ext_vector_type(4)));

// ---- gemm: blocks 0..390: per wave 16 rows -> fph(f16), inv_norm, baseh(f16).
//      block 391: write pre-swizzled f16 W1 table (32KB) for main_kernel. ----
__global__ __launch_bounds__(512) void gemm_kernel(const float* __restrict__ fp,
                                                   const float* __restrict__ W,
                                                   const float* __restrict__ b,
                                                   f16* __restrict__ fph,
                                                   f16* __restrict__ baseh,
                                                   float* __restrict__ inv_norm,
                                                   f16* __restrict__ W1h) {
    int tid = threadIdx.x;
    if (blockIdx.x == 391) {
        // W1h[c*128 + ((k0>>3)^(c&15))*8 + e] = (f16)W[c*256 + k0 + e]
        #pragma unroll
        for (int it = 0; it < 4; ++it) {
            int g = tid + it * 512;
            int i = g * 8;
            int c = i >> 7, k0 = i & 127;
            int chunk = (k0 >> 3) ^ (c & 15);
            f32x4 v0 = *(const f32x4*)(W + (size_t)c * 256 + k0);
            f32x4 v1 = *(const f32x4*)(W + (size_t)c * 256 + k0 + 4);
            f16x8 h;
            #pragma unroll
            for (int e = 0; e < 4; ++e) { h[e] = (f16)v0[e]; h[4 + e] = (f16)v1[e]; }
            *(f16x8*)(W1h + c * 128 + chunk * 8) = h;
        }
        return;
    }

    __shared__ f16 wlds[128 * 128];  // W2[col][k], chunk-swizzled: chunk ^= (col&15)
    #pragma unroll
    for (int it = 0; it < 4; ++it) {
        int g = tid + it * 512;
        int i = g * 8;
        int c = i >> 7, k0 = i & 127;
        int chunk = (k0 >> 3) ^ (c & 15);
        f32x4 v0 = *(const f32x4*)(W + (size_t)c * 256 + 128 + k0);
        f32x4 v1 = *(const f32x4*)(W + (size_t)c * 256 + 128 + k0 + 4);
        f16x8 h;
        #pragma unroll
        for (int e = 0; e < 4; ++e) { h[e] = (f16)v0[e]; h[4 + e] = (f16)v1[e]; }
        *(f16x8*)(wlds + c * 128 + chunk * 8) = h;
    }
    __syncthreads();

    int wid = tid >> 6, lane = tid & 63;
    int row0 = blockIdx.x * 128 + wid * 16;
    if (row0 >= NROWS) return;         // no barriers after this point
    int r = lane & 15, kg = lane >> 4;

    const float* src = fp + (size_t)(row0 + r) * D + kg * 8;
    f32x4 v[8];
    float ssq = 0.f;
    #pragma unroll
    for (int kc = 0; kc < 4; ++kc) {
        v[2 * kc]     = *(const f32x4*)(src + kc * 32);
        v[2 * kc + 1] = *(const f32x4*)(src + kc * 32 + 4);
        #pragma unroll
        for (int e = 0; e < 4; ++e) {
            ssq = fmaf(v[2 * kc][e], v[2 * kc][e], ssq);
            ssq = fmaf(v[2 * kc + 1][e], v[2 * kc + 1][e], ssq);
        }
    }
    ssq += __shfl_xor(ssq, 16, 64);
    ssq += __shfl_xor(ssq, 32, 64);
    if (kg == 0) inv_norm[row0 + r] = rsqrtf(ssq);

    f16x8 a[4];
    #pragma unroll
    for (int kc = 0; kc < 4; ++kc) {
        f16x8 h;
        #pragma unroll
        for (int e = 0; e < 4; ++e) { h[e] = (f16)v[2 * kc][e]; h[4 + e] = (f16)v[2 * kc + 1][e]; }
        a[kc] = h;
        *(f16x8*)(fph + (size_t)(row0 + r) * D + kc * 32 + kg * 8) = h;
    }

    #pragma unroll
    for (int ct = 0; ct < 8; ++ct) {
        int col = ct * 16 + r;
        f32x4 acc = {0.f, 0.f, 0.f, 0.f};
        #pragma unroll
        for (int kc = 0; kc < 4; ++kc) {
            int sc = (kc * 4 + kg) ^ r;  // matches staging XOR
            f16x8 bf = *(const f16x8*)(wlds + col * 128 + sc * 8);
            acc = __builtin_amdgcn_mfma_f32_16x16x32_f16(a[kc], bf, acc, 0, 0, 0);
        }
        float bias = b[col];
        #pragma unroll
        for (int i = 0; i < 4; ++i)
            baseh[(size_t)(row0 + kg * 4 + i) * D + col] = (f16)(acc[i] + bias);
    }
}

// ---- main: 1024-thread blocks (16 waves share one 32KB W1 tile; 2 blocks/CU -> 32 waves/CU).
//      One pair per wave; all gathers issued before the barrier; Y recomputed via MFMA. ----
__global__ __launch_bounds__(1024, 8) void main_kernel(const f16* __restrict__ W1h,
                                                       const f16* __restrict__ fph,
                                                       const f16* __restrict__ baseh,
                                                       const int* __restrict__ idx,
                                                       const float* __restrict__ inv_norm,
                                                       float* __restrict__ out) {
    __shared__ f16 wlds[128 * 128];  // pre-swizzled W1, plain copy
    int tid = threadIdx.x;
    {
        const f16x8* srcv = (const f16x8*)W1h;
        f16x8* dstv = (f16x8*)wlds;
        dstv[tid] = srcv[tid];
        dstv[tid + 1024] = srcv[tid + 1024];
    }

    int wave = tid >> 6, lane = tid & 63;
    int r = lane & 15, kg = lane >> 4;
    int pw = blockIdx.x * 16 + wave;     // pair id, 0..24999
    bool valid = pw < NROWS / 2;
    int n0 = 2 * pw, n1 = n0 + 1;

    int ja = 0, jb = 0;
    float rna = 0.f, rnb = 0.f;
    f16x8 y0[4], y1[4], aa[4], ab[4];
    float bha[8], bhb[8], rja[4], rjb[4];

    if (valid) {
        // --- issue every global load before the barrier (overlap with staging) ---
        ja = idx[(size_t)n0 * KNB + r];
        jb = idx[(size_t)n1 * KNB + r];
        rna = inv_norm[n0]; rnb = inv_norm[n1];
        #pragma unroll
        for (int kc = 0; kc < 4; ++kc) {
            y0[kc] = *(const f16x8*)(fph + (size_t)n0 * D + kc * 32 + kg * 8);
            y1[kc] = *(const f16x8*)(fph + (size_t)n1 * D + kc * 32 + kg * 8);
        }
        #pragma unroll
        for (int ct = 0; ct < 8; ++ct) {
            bha[ct] = (float)baseh[(size_t)n0 * D + ct * 16 + r];
            bhb[ct] = (float)baseh[(size_t)n1 * D + ct * 16 + r];
        }
        #pragma unroll
        for (int kc = 0; kc < 4; ++kc) {
            aa[kc] = *(const f16x8*)(fph + (size_t)ja * D + kc * 32 + kg * 8);
            ab[kc] = *(const f16x8*)(fph + (size_t)jb * D + kc * 32 + kg * 8);
        }
        #pragma unroll
        for (int i = 0; i < 4; ++i) {
            rja[i] = inv_norm[__shfl(ja, kg * 4 + i, 64)];
            rjb[i] = inv_norm[__shfl(jb, kg * 4 + i, 64)];
        }
    }

    __syncthreads();                     // wlds ready
    if (!valid) return;

    // cosine via MFMA: C[row=k][*] = dot(fp[j_k], fp[n])
    f32x4 ca = {0.f, 0.f, 0.f, 0.f}, cb = {0.f, 0.f, 0.f, 0.f};
    #pragma unroll
    for (int kc = 0; kc < 4; ++kc)
        ca = __builtin_amdgcn_mfma_f32_16x16x32_f16(aa[kc], y0[kc], ca, 0, 0, 0);
    #pragma unroll
    for (int kc = 0; kc < 4; ++kc)
        cb = __builtin_amdgcn_mfma_f32_16x16x32_f16(ab[kc], y1[kc], cb, 0, 0, 0);
    float wa[4], wb[4];
    #pragma unroll
    for (int i = 0; i < 4; ++i) {
        wa[i] = ca[i] * rna * rja[i];
        wb[i] = cb[i] * rnb * rjb[i];
    }

    // Y-recompute + combine; C-in = base (broadcast over the 4 k-rows)
    #pragma unroll
    for (int ct = 0; ct < 8; ++ct) {
        f32x4 acc0 = {bha[ct], bha[ct], bha[ct], bha[ct]};
        f32x4 acc1 = {bhb[ct], bhb[ct], bhb[ct], bhb[ct]};
        #pragma unroll
        for (int kc = 0; kc < 4; ++kc) {
            int sc = (kc * 4 + kg) ^ r;
            f16x8 bf = *(const f16x8*)(wlds + (ct * 16 + r) * 128 + sc * 8);
            acc0 = __builtin_amdgcn_mfma_f32_16x16x32_f16(aa[kc], bf, acc0, 0, 0, 0);
            acc1 = __builtin_amdgcn_mfma_f32_16x16x32_f16(ab[kc], bf, acc1, 0, 0, 0);
        }
        float m0 = -INFINITY, m1 = -INFINITY;
        #pragma unroll
        for (int i = 0; i < 4; ++i) {    // C row kg*4+i = neighbor k index
            m0 = fmaxf(m0, acc0[i] * wa[i]);
            m1 = fmaxf(m1, acc1[i] * wb[i]);
        }
        m0 = fmaxf(m0, __shfl_xor(m0, 16, 64));
        m0 = fmaxf(m0, __shfl_xor(m0, 32, 64));
        m1 = fmaxf(m1, __shfl_xor(m1, 16, 64));
        m1 = fmaxf(m1, __shfl_xor(m1, 32, 64));
        if (kg == 0) {
            out[(size_t)n0 * D + ct * 16 + r] = m0;
            out[(size_t)n1 * D + ct * 16 + r] = m1;
        }
    }
}

extern "C" void kernel_launch(void* const* d_in, const int* in_sizes, int n_in,
                              void* d_out, int out_size, void* d_ws, size_t ws_size,
                              hipStream_t stream) {
    const float* fp  = (const float*)d_in[0];   // (N,128) f32
    const int*   idx = (const int*)d_in[1];     // (N,16) int32
    const float* W   = (const float*)d_in[2];   // (128,256) f32
    const float* b   = (const float*)d_in[3];   // (128,) f32
    float* out = (float*)d_out;                 // (N,128) f32

    char* ws = (char*)d_ws;
    f16* fph   = (f16*)ws;                                   // 12.8 MB
    f16* baseh = fph + (size_t)NROWS * D;                    // 12.8 MB
    float* inv_norm = (float*)(ws + (size_t)2 * NROWS * D * 2);  // 200 KB
    f16* W1h = (f16*)(ws + (size_t)2 * NROWS * D * 2 + NROWS * 4);  // 32 KB

    gemm_kernel<<<392, 512, 0, stream>>>(fp, W, b, fph, baseh, inv_norm, W1h);
    main_kernel<<<(NROWS / 2 + 15) / 16, 1024, 0, stream>>>(W1h, fph, baseh, idx, inv_norm, out);
}

// Round 9
// 141.179 us; speedup vs baseline: 2.8477x; 2.8477x over previous
//
#include <hip/hip_runtime.h>
#include <hip/hip_fp16.h>
#include <math.h>

#define NROWS 50000
#define D 128
#define KNB 16

typedef _Float16 f16;
typedef _Float16 f16x8 __attribute__((ext_vector_type(8)));
typedef float f32x4 __attribute__((ext_vector_type(4)));

// ---- gemm: blocks 0..390: per wave 16 rows -> fph(f16), inv_norm, baseh(f16).
//      block 391: write linear f16 W1 table (32KB) for main_kernel. ----
__global__ __launch_bounds__(512) void gemm_kernel(const float* __restrict__ fp,
                                                   const float* __restrict__ W,
                                                   const float* __restrict__ b,
                                                   f16* __restrict__ fph,
                                                   f16* __restrict__ baseh,
                                                   float* __restrict__ inv_norm,
                                                   f16* __restrict__ W1h) {
    int tid = threadIdx.x;
    if (blockIdx.x == 391) {
        // W1h[c*128 + k] = (f16)W[c*256 + k]  (linear, L1-friendly)
        #pragma unroll
        for (int it = 0; it < 4; ++it) {
            int g = tid + it * 512;
            int i = g * 8;
            int c = i >> 7, k0 = i & 127;
            f32x4 v0 = *(const f32x4*)(W + (size_t)c * 256 + k0);
            f32x4 v1 = *(const f32x4*)(W + (size_t)c * 256 + k0 + 4);
            f16x8 h;
            #pragma unroll
            for (int e = 0; e < 4; ++e) { h[e] = (f16)v0[e]; h[4 + e] = (f16)v1[e]; }
            *(f16x8*)(W1h + c * 128 + k0) = h;
        }
        return;
    }

    __shared__ f16 wlds[128 * 128];  // W2[col][k], chunk-swizzled: chunk ^= (col&15)
    #pragma unroll
    for (int it = 0; it < 4; ++it) {
        int g = tid + it * 512;
        int i = g * 8;
        int c = i >> 7, k0 = i & 127;
        int chunk = (k0 >> 3) ^ (c & 15);
        f32x4 v0 = *(const f32x4*)(W + (size_t)c * 256 + 128 + k0);
        f32x4 v1 = *(const f32x4*)(W + (size_t)c * 256 + 128 + k0 + 4);
        f16x8 h;
        #pragma unroll
        for (int e = 0; e < 4; ++e) { h[e] = (f16)v0[e]; h[4 + e] = (f16)v1[e]; }
        *(f16x8*)(wlds + c * 128 + chunk * 8) = h;
    }
    __syncthreads();

    int wid = tid >> 6, lane = tid & 63;
    int row0 = blockIdx.x * 128 + wid * 16;
    if (row0 >= NROWS) return;         // no barriers after this point
    int r = lane & 15, kg = lane >> 4;

    const float* src = fp + (size_t)(row0 + r) * D + kg * 8;
    f32x4 v[8];
    float ssq = 0.f;
    #pragma unroll
    for (int kc = 0; kc < 4; ++kc) {
        v[2 * kc]     = *(const f32x4*)(src + kc * 32);
        v[2 * kc + 1] = *(const f32x4*)(src + kc * 32 + 4);
        #pragma unroll
        for (int e = 0; e < 4; ++e) {
            ssq = fmaf(v[2 * kc][e], v[2 * kc][e], ssq);
            ssq = fmaf(v[2 * kc + 1][e], v[2 * kc + 1][e], ssq);
        }
    }
    ssq += __shfl_xor(ssq, 16, 64);
    ssq += __shfl_xor(ssq, 32, 64);
    if (kg == 0) inv_norm[row0 + r] = rsqrtf(ssq);

    f16x8 a[4];
    #pragma unroll
    for (int kc = 0; kc < 4; ++kc) {
        f16x8 h;
        #pragma unroll
        for (int e = 0; e < 4; ++e) { h[e] = (f16)v[2 * kc][e]; h[4 + e] = (f16)v[2 * kc + 1][e]; }
        a[kc] = h;
        *(f16x8*)(fph + (size_t)(row0 + r) * D + kc * 32 + kg * 8) = h;
    }

    #pragma unroll
    for (int ct = 0; ct < 8; ++ct) {
        int col = ct * 16 + r;
        f32x4 acc = {0.f, 0.f, 0.f, 0.f};
        #pragma unroll
        for (int kc = 0; kc < 4; ++kc) {
            int sc = (kc * 4 + kg) ^ r;  // matches staging XOR
            f16x8 bf = *(const f16x8*)(wlds + col * 128 + sc * 8);
            acc = __builtin_amdgcn_mfma_f32_16x16x32_f16(a[kc], bf, acc, 0, 0, 0);
        }
        float bias = b[col];
        #pragma unroll
        for (int i = 0; i < 4; ++i)
            baseh[(size_t)(row0 + kg * 4 + i) * D + col] = (f16)(acc[i] + bias);
    }
}

// ---- main: NO LDS, NO barrier. One pair per wave; W1 f16 read from global
//      (32KB -> L1-resident). Gathers issue at wave start; Y recomputed via MFMA. ----
__global__ __launch_bounds__(256) void main_kernel(const f16* __restrict__ W1h,
                                                   const f16* __restrict__ fph,
                                                   const f16* __restrict__ baseh,
                                                   const int* __restrict__ idx,
                                                   const float* __restrict__ inv_norm,
                                                   float* __restrict__ out) {
    int wid = threadIdx.x >> 6, lane = threadIdx.x & 63;
    int r = lane & 15, kg = lane >> 4;
    int pw = blockIdx.x * 4 + wid;       // pair id, 0..24999
    int n0 = 2 * pw, n1 = n0 + 1;

    // --- all global loads issue immediately (no barrier in this kernel) ---
    int ja = idx[(size_t)n0 * KNB + r];
    int jb = idx[(size_t)n1 * KNB + r];
    float rna = inv_norm[n0], rnb = inv_norm[n1];

    f16x8 y0[4], y1[4];                  // B-frags for cosine: broadcast rows n0/n1
    #pragma unroll
    for (int kc = 0; kc < 4; ++kc) {
        y0[kc] = *(const f16x8*)(fph + (size_t)n0 * D + kc * 32 + kg * 8);
        y1[kc] = *(const f16x8*)(fph + (size_t)n1 * D + kc * 32 + kg * 8);
    }
    float bha[8], bhb[8];
    #pragma unroll
    for (int ct = 0; ct < 8; ++ct) {
        bha[ct] = (float)baseh[(size_t)n0 * D + ct * 16 + r];
        bhb[ct] = (float)baseh[(size_t)n1 * D + ct * 16 + r];
    }
    f16x8 aa[4], ab[4];                  // gathered neighbor rows
    #pragma unroll
    for (int kc = 0; kc < 4; ++kc) {
        aa[kc] = *(const f16x8*)(fph + (size_t)ja * D + kc * 32 + kg * 8);
        ab[kc] = *(const f16x8*)(fph + (size_t)jb * D + kc * 32 + kg * 8);
    }
    float rja[4], rjb[4];
    #pragma unroll
    for (int i = 0; i < 4; ++i) {
        rja[i] = inv_norm[__shfl(ja, kg * 4 + i, 64)];
        rjb[i] = inv_norm[__shfl(jb, kg * 4 + i, 64)];
    }

    // cosine via MFMA: C[row=k][*] = dot(fp[j_k], fp[n])
    f32x4 ca = {0.f, 0.f, 0.f, 0.f}, cb = {0.f, 0.f, 0.f, 0.f};
    #pragma unroll
    for (int kc = 0; kc < 4; ++kc)
        ca = __builtin_amdgcn_mfma_f32_16x16x32_f16(aa[kc], y0[kc], ca, 0, 0, 0);
    #pragma unroll
    for (int kc = 0; kc < 4; ++kc)
        cb = __builtin_amdgcn_mfma_f32_16x16x32_f16(ab[kc], y1[kc], cb, 0, 0, 0);
    float wa[4], wb[4];
    #pragma unroll
    for (int i = 0; i < 4; ++i) {
        wa[i] = ca[i] * rna * rja[i];
        wb[i] = cb[i] * rnb * rjb[i];
    }

    // Y-recompute + combine; B-frags from global W1h (L1-resident); C-in = base
    #pragma unroll
    for (int ct = 0; ct < 8; ++ct) {
        f32x4 acc0 = {bha[ct], bha[ct], bha[ct], bha[ct]};
        f32x4 acc1 = {bhb[ct], bhb[ct], bhb[ct], bhb[ct]};
        #pragma unroll
        for (int kc = 0; kc < 4; ++kc) {
            f16x8 bf = *(const f16x8*)(W1h + (size_t)(ct * 16 + r) * 128 + (kc * 4 + kg) * 8);
            acc0 = __builtin_amdgcn_mfma_f32_16x16x32_f16(aa[kc], bf, acc0, 0, 0, 0);
            acc1 = __builtin_amdgcn_mfma_f32_16x16x32_f16(ab[kc], bf, acc1, 0, 0, 0);
        }
        float m0 = -INFINITY, m1 = -INFINITY;
        #pragma unroll
        for (int i = 0; i < 4; ++i) {    // C row kg*4+i = neighbor k index
            m0 = fmaxf(m0, acc0[i] * wa[i]);
            m1 = fmaxf(m1, acc1[i] * wb[i]);
        }
        m0 = fmaxf(m0, __shfl_xor(m0, 16, 64));
        m0 = fmaxf(m0, __shfl_xor(m0, 32, 64));
        m1 = fmaxf(m1, __shfl_xor(m1, 16, 64));
        m1 = fmaxf(m1, __shfl_xor(m1, 32, 64));
        if (kg == 0) {
            out[(size_t)n0 * D + ct * 16 + r] = m0;
            out[(size_t)n1 * D + ct * 16 + r] = m1;
        }
    }
}

extern "C" void kernel_launch(void* const* d_in, const int* in_sizes, int n_in,
                              void* d_out, int out_size, void* d_ws, size_t ws_size,
                              hipStream_t stream) {
    const float* fp  = (const float*)d_in[0];   // (N,128) f32
    const int*   idx = (const int*)d_in[1];     // (N,16) int32
    const float* W   = (const float*)d_in[2];   // (128,256) f32
    const float* b   = (const float*)d_in[3];   // (128,) f32
    float* out = (float*)d_out;                 // (N,128) f32

    char* ws = (char*)d_ws;
    f16* fph   = (f16*)ws;                                   // 12.8 MB
    f16* baseh = fph + (size_t)NROWS * D;                    // 12.8 MB
    float* inv_norm = (float*)(ws + (size_t)2 * NROWS * D * 2);  // 200 KB
    f16* W1h = (f16*)(ws + (size_t)2 * NROWS * D * 2 + NROWS * 4);  // 32 KB

    gemm_kernel<<<392, 512, 0, stream>>>(fp, W, b, fph, baseh, inv_norm, W1h);
    main_kernel<<<(NROWS / 2 + 3) / 4, 256, 0, stream>>>(W1h, fph, baseh, idx, inv_norm, out);
}

// Round 10
// 64.181 us; speedup vs baseline: 6.2640x; 2.1997x over previous
//
#include <hip/hip_runtime.h>
#include <hip/hip_fp16.h>
#include <math.h>

#define NROWS 50000
#define D 128
#define KNB 16

typedef _Float16 f16;
typedef _Float16 f16x8 __attribute__((ext_vector_type(8)));
typedef _Float16 f16x2 __attribute__((ext_vector_type(2)));
typedef float f32x4 __attribute__((ext_vector_type(4)));
typedef float f32x2 __attribute__((ext_vector_type(2)));
typedef unsigned int u32;

// ---- fused gemm: W->LDS(f16,swizzled,64KB); per wave 16 rows:
//      fp8 e4m3 normalized row (cosine table), Yh(f16), base (f16 in ws OR f32 in out) ----
__global__ __launch_bounds__(512) void gemm_kernel(const float* __restrict__ fp,
                                                   const float* __restrict__ W,
                                                   const float* __restrict__ b,
                                                   unsigned char* __restrict__ fp8n,
                                                   f16* __restrict__ Yh,
                                                   f16* __restrict__ baseh,
                                                   float* __restrict__ basef,
                                                   int use16) {
    __shared__ f16 wlds[256 * 128];  // Wcat[col][k], chunk-swizzled: chunk ^= (col&15)
    int tid = threadIdx.x;
    int wid = tid >> 6, lane = tid & 63;
    int row0 = blockIdx.x * 128 + wid * 16;
    int r = lane & 15, kg = lane >> 4;
    bool valid = row0 < NROWS;

    // --- hoist fp row loads: issue before staging so latency overlaps it ---
    f32x4 v[8];
    if (valid) {
        const float* src = fp + (size_t)(row0 + r) * D + kg * 8;
        #pragma unroll
        for (int kc = 0; kc < 4; ++kc) {
            v[2 * kc]     = *(const f32x4*)(src + kc * 32);
            v[2 * kc + 1] = *(const f32x4*)(src + kc * 32 + 4);
        }
    }

    // stage W (128x256 f32) -> LDS as f16 concat layout, coalesced 32B reads per thread
    #pragma unroll
    for (int it = 0; it < 8; ++it) {
        int g = tid + it * 512;          // 8-float group, 4096 total
        int i = g * 8;                   // flat index into W
        int c_w = i >> 8;                // W row (0..127)
        int kk = i & 255;                // W col (0..255)
        int destrow = (kk < 128) ? c_w : c_w + 128;
        int k = kk & 127;
        int chunk = (k >> 3) ^ (destrow & 15);
        f32x4 v0 = *(const f32x4*)(W + i);
        f32x4 v1 = *(const f32x4*)(W + i + 4);
        f16x8 h;
        #pragma unroll
        for (int e = 0; e < 4; ++e) { h[e] = (f16)v0[e]; h[4 + e] = (f16)v1[e]; }
        *(f16x8*)(wlds + destrow * 128 + chunk * 8) = h;
    }
    __syncthreads();
    if (!valid) return;

    float ssq = 0.f;
    #pragma unroll
    for (int q = 0; q < 8; ++q) {
        #pragma unroll
        for (int e = 0; e < 4; ++e) ssq = fmaf(v[q][e], v[q][e], ssq);
    }
    ssq += __shfl_xor(ssq, 16, 64);
    ssq += __shfl_xor(ssq, 32, 64);      // all lanes: full row ssq
    float rn = rsqrtf(ssq);

    // A-frags (f16, unnormalized) for MFMA + fp8 e4m3 normalized row for the cosine table
    f16x8 a[4];
    #pragma unroll
    for (int kc = 0; kc < 4; ++kc) {
        f16x8 h;
        float nx[8];
        #pragma unroll
        for (int e = 0; e < 4; ++e) {
            float x0 = v[2 * kc][e], x1 = v[2 * kc + 1][e];
            h[e] = (f16)x0;        h[4 + e] = (f16)x1;
            nx[e] = x0 * rn;       nx[4 + e] = x1 * rn;
        }
        a[kc] = h;
        u32 lo = __builtin_amdgcn_cvt_pk_fp8_f32(nx[0], nx[1], 0u, false);
        lo     = __builtin_amdgcn_cvt_pk_fp8_f32(nx[2], nx[3], lo, true);
        u32 hi = __builtin_amdgcn_cvt_pk_fp8_f32(nx[4], nx[5], 0u, false);
        hi     = __builtin_amdgcn_cvt_pk_fp8_f32(nx[6], nx[7], hi, true);
        uint2 st; st.x = lo; st.y = hi;
        *(uint2*)(fp8n + (size_t)(row0 + r) * 128 + kc * 32 + kg * 8) = st;
    }

    #pragma unroll 4
    for (int ct = 0; ct < 16; ++ct) {
        int col = ct * 16 + r;
        f32x4 acc = {0.f, 0.f, 0.f, 0.f};
        #pragma unroll
        for (int kc = 0; kc < 4; ++kc) {
            int sc = (kc * 4 + kg) ^ r;  // swizzled chunk (matches staging XOR)
            f16x8 bf = *(const f16x8*)(wlds + col * 128 + sc * 8);
            acc = __builtin_amdgcn_mfma_f32_16x16x32_f16(a[kc], bf, acc, 0, 0, 0);
        }
        // C/D: col = lane&15 -> output channel; rows = row0 + kg*4 + i
        if (col < 128) {
            #pragma unroll
            for (int i = 0; i < 4; ++i)
                Yh[(size_t)(row0 + kg * 4 + i) * D + col] = (f16)acc[i];
        } else {
            float bias = b[col - 128];
            if (use16) {
                #pragma unroll
                for (int i = 0; i < 4; ++i)
                    baseh[(size_t)(row0 + kg * 4 + i) * D + (col - 128)] = (f16)(acc[i] + bias);
            } else {
                #pragma unroll
                for (int i = 0; i < 4; ++i)
                    basef[(size_t)(row0 + kg * 4 + i) * D + (col - 128)] = acc[i] + bias;
            }
        }
    }
}

// ---- main: one wave per n (round-5 structure); all 16 Y-gathers issued first;
//      fp8 cosine dots; base read f16 (ws) or f32 (out) ----
__global__ __launch_bounds__(256) void main_kernel(const unsigned char* __restrict__ fp8n,
                                                   const int* __restrict__ idx,
                                                   const f16* __restrict__ Yh,
                                                   const f16* __restrict__ baseh,
                                                   float* __restrict__ out,
                                                   int use16) {
    int wid = threadIdx.x >> 6, lane = threadIdx.x & 63;
    int n = blockIdx.x * 4 + wid;
    int s = lane & 3, k = lane >> 2;

    int j = idx[(size_t)n * KNB + k];

    // issue the full Y gather set up front (memory-level parallelism)
    f16x2 yv[16];
    #pragma unroll
    for (int kk = 0; kk < KNB; ++kk) {
        int jk = __shfl(j, kk * 4, 64);
        yv[kk] = *(const f16x2*)(Yh + (size_t)jk * D + lane * 2);
    }
    float2 bv;
    if (use16) {
        f16x2 t = *(const f16x2*)(baseh + (size_t)n * D + lane * 2);
        bv.x = (float)t[0];
        bv.y = (float)t[1];
    } else {
        bv = *(const float2*)(out + (size_t)n * D + lane * 2);
    }

    // cosine dot on fp8-normalized rows: lane = (k, 32-elem slice s); w = dot directly
    const uint4* pj = (const uint4*)(fp8n + (size_t)j * 128 + s * 32);
    const uint4* pn = (const uint4*)(fp8n + (size_t)n * 128 + s * 32);
    uint4 xa = pj[0], xb = pj[1];
    uint4 ya = pn[0], yb = pn[1];
    float p = 0.f;
    auto dot4 = [&p](u32 xw, u32 yw) {
        f32x2 x0 = __builtin_amdgcn_cvt_pk_f32_fp8(xw, false);
        f32x2 x1 = __builtin_amdgcn_cvt_pk_f32_fp8(xw, true);
        f32x2 y0 = __builtin_amdgcn_cvt_pk_f32_fp8(yw, false);
        f32x2 y1 = __builtin_amdgcn_cvt_pk_f32_fp8(yw, true);
        p = fmaf(x0.x, y0.x, p); p = fmaf(x0.y, y0.y, p);
        p = fmaf(x1.x, y1.x, p); p = fmaf(x1.y, y1.y, p);
    };
    dot4(xa.x, ya.x); dot4(xa.y, ya.y); dot4(xa.z, ya.z); dot4(xa.w, ya.w);
    dot4(xb.x, yb.x); dot4(xb.y, yb.y); dot4(xb.z, yb.z); dot4(xb.w, yb.w);
    p += __shfl_xor(p, 1, 64);
    p += __shfl_xor(p, 2, 64);

    // combine: lane owns cols 2*lane, 2*lane+1
    float a0 = -INFINITY, a1 = -INFINITY;
    #pragma unroll
    for (int kk = 0; kk < KNB; ++kk) {
        float wk = __shfl(p, kk * 4, 64);
        a0 = fmaxf(a0, ((float)yv[kk][0] + bv.x) * wk);
        a1 = fmaxf(a1, ((float)yv[kk][1] + bv.y) * wk);
    }
    *(float2*)(out + (size_t)n * D + lane * 2) = make_float2(a0, a1);
}

extern "C" void kernel_launch(void* const* d_in, const int* in_sizes, int n_in,
                              void* d_out, int out_size, void* d_ws, size_t ws_size,
                              hipStream_t stream) {
    const float* fp  = (const float*)d_in[0];   // (N,128) f32
    const int*   idx = (const int*)d_in[1];     // (N,16) int32
    const float* W   = (const float*)d_in[2];   // (128,256) f32
    const float* b   = (const float*)d_in[3];   // (128,) f32
    float* out = (float*)d_out;                 // (N,128) f32

    char* ws = (char*)d_ws;
    unsigned char* fp8n = (unsigned char*)ws;            // 6.4 MB (fp8 e4m3 normalized rows)
    f16* Yh    = (f16*)(ws + (size_t)NROWS * 128);       // 12.8 MB
    f16* baseh = (f16*)(ws + (size_t)3 * NROWS * 128);   // 12.8 MB (only if ws large enough)

    // baseh path needs 32e6 bytes of workspace; otherwise keep base f32 in `out` (round-5 path)
    int use16 = (ws_size >= (size_t)4 * NROWS * 128) ? 1 : 0;

    gemm_kernel<<<(NROWS + 127) / 128, 512, 0, stream>>>(fp, W, b, fp8n, Yh, baseh, out, use16);
    main_kernel<<<NROWS / 4, 256, 0, stream>>>(fp8n, idx, Yh, baseh, out, use16);
}